// Round 3
// baseline (18297.394 us; speedup 1.0000x reference)
//
#include <hip/hip_runtime.h>

// EA-LSTM fused kernel, v4: full fp32, 2-CU teams, register-resident weights.
//
// v2/v3 post-mortem: c_n error ~85 regardless of WHICH path was f16 ->
// the recurrence amplifies ANY per-step gate noise by ~1e5-1e6 (sf~1
// integration + identity-diagonal feedback). Only fp32 everywhere passes
// (v1: 0.5 <= 2.17). fp32 weights (882 KB) exceed one CU (512 KB RF +
// 160 KB LDS) -> split across a 2-CU team.
//
// Layout: 256 blocks (1/CU, all co-resident: grid <= #CUs), team = blk>>1,
// role = blk&1. Role r owns output units [128r,128r+128) i.e. W_hh columns
// {128r+a, 256+128r+a, 512+128r+a}, ALL 256 K-rows: thread (kq=t>>7,a=t&127)
// holds rows [64kq,64kq+64) x 3 cols = 192 fp32 VGPRs. W_ih half in LDS
// (48 KB). Team processes TWO batch elements (team, team+128) concurrently
// in one 365-step pass -> 221K MAC/CU/step, ~1730 cyc FMA floor.
//
// Cross-CU exchange per step: gate lanes write h to hn_out (required output
// anyway); partner reads the other 128-unit half directly from hn_out after
// an agent-scope acquire on a monotone step-flag in d_ws. Own-half h comes
// from LDS. Step 0 skips the exchange (h0=0). Startup rendezvous through
// cn_out row 364 (harness memsets out before launch; words legit-overwritten
// only at step 364, long after the last rendezvous read) -> stale-ws/replay
// safe: each role zeroes its ws flag BEFORE posting its ready magic.

#define BB 256
#define SS 365
#define FD 32
#define FS 27
#define HH 256
#define NT 512
typedef unsigned int u32;

#define MAC4C(HA, HB, WF, WO, WG) \
    acc00 = fmaf(HA, WF, acc00); acc01 = fmaf(HA, WO, acc01); acc02 = fmaf(HA, WG, acc02); \
    acc10 = fmaf(HB, WF, acc10); acc11 = fmaf(HB, WO, acc11); acc12 = fmaf(HB, WG, acc12);

#define MAC16(A, B, J) \
    MAC4C(A.x, B.x, wf[4*(J)+0], wo[4*(J)+0], wg[4*(J)+0]) \
    MAC4C(A.y, B.y, wf[4*(J)+1], wo[4*(J)+1], wg[4*(J)+1]) \
    MAC4C(A.z, B.z, wf[4*(J)+2], wo[4*(J)+2], wg[4*(J)+2]) \
    MAC4C(A.w, B.w, wf[4*(J)+3], wo[4*(J)+3], wg[4*(J)+3])

__global__ __launch_bounds__(NT, 2) void ealstm_kernel(
    const float* __restrict__ x_d, const float* __restrict__ x_s,
    const float* __restrict__ W_ih, const float* __restrict__ W_hh,
    const float* __restrict__ W_sh, const float* __restrict__ bias,
    const float* __restrict__ bias_s, const float* __restrict__ W_fc,
    const float* __restrict__ b_fc, float* __restrict__ d_out,
    u32* __restrict__ ws)
{
    __shared__ __align__(16) float sm_wih[FD][3][128];   // 48 KB  W_ih half
    __shared__ __align__(16) float sm_part[2][3][4][128];// 12 KB  [elem][gate][kq][a]
    __shared__ __align__(16) float hbuf[2][128];         // own-half h per elem
    __shared__ __align__(16) float xbuf[2][2][FD];       // x rows, dbl-buffered
    __shared__ float outp[2][2];                         // fc wave partials

    const int t = threadIdx.x;
    const int blk = blockIdx.x;
    const int team = blk >> 1, role = blk & 1;
    const int e0 = team, e1 = team + 128;
    const int kq = t >> 7, a = t & 127;
    const bool own_half = ((kq >> 1) == role);           // wave-uniform

    float* __restrict__ out_fc = d_out;                      // [B,S,1]
    float* __restrict__ hn_out = d_out + (size_t)BB * SS;    // [B,S,H]
    float* __restrict__ cn_out = hn_out + (size_t)BB * SS * HH;

    u32* flag_my = ws + (size_t)(team * 2 + role) * 16;
    u32* flag_pt = ws + (size_t)(team * 2 + (1 ^ role)) * 16;
    float* fcp_my = (float*)(ws + 4096) + (team * 2 + role) * 4;
    float* fcp_pt = (float*)(ws + 4096) + (team * 2 + (1 ^ role)) * 4;

    // ---- resident weights: rows [64kq,64kq+64) x cols {128r+a +256g}
    float wf[64], wo[64], wg[64];
    {
        const float* base = W_hh + (size_t)(64 * kq) * 768 + 128 * role + a;
#pragma unroll
        for (int j = 0; j < 64; ++j) {
            wf[j] = base[(size_t)j * 768];
            wo[j] = base[(size_t)j * 768 + 256];
            wg[j] = base[(size_t)j * 768 + 512];
        }
    }
    // ---- W_ih half -> LDS
    for (int idx = t; idx < FD * 384; idx += NT) {
        const int k = idx / 384, rem = idx - k * 384;
        const int g = rem >> 7, cc = rem & 127;
        sm_wih[k][g][cc] = W_ih[(size_t)k * 768 + g * 256 + 128 * role + cc];
    }
    // ---- x row 0 for both elements
    if (t < 64) {
        const int e = t >> 5, lane = t & 31;
        xbuf[0][e][lane] = x_d[(size_t)(e ? e1 : e0) * SS * FD + lane];
    }
    // ---- gate-lane constants/state (threads 0..255: elem t>>7, unit 128r+(t&127))
    float c_state = 0.f, igv = 0.f, bfv = 0.f, bov = 0.f, bgv = 0.f, wfcv = 0.f;
    if (t < 256) {
        const int e = t >> 7, i = t & 127, u = 128 * role + i;
        const int eb = e ? e1 : e0;
        float accs = bias_s[u];
        for (int k = 0; k < FS; ++k)
            accs = fmaf(x_s[(size_t)eb * FS + k], W_sh[(size_t)k * HH + u], accs);
        igv = 1.f / (1.f + __expf(-accs));
        bfv = bias[u]; bov = bias[HH + u]; bgv = bias[2 * HH + u];
        wfcv = W_fc[u];
        hbuf[e][i] = 0.f;                         // h0 = 0
    }
    const float bfc = b_fc[0];

    // ---- startup rendezvous (stale-ws safe: zero own flag BEFORE ready magic)
    u32* rdy_my = (u32*)(cn_out + ((size_t)e0 * SS + (SS - 1)) * HH + 128 * role);
    u32* rdy_pt = (u32*)(cn_out + ((size_t)e0 * SS + (SS - 1)) * HH + 128 * (1 ^ role));
    if (t == 0) {
        __hip_atomic_store(flag_my, 0u, __ATOMIC_RELAXED, __HIP_MEMORY_SCOPE_AGENT);
        __threadfence();
        __hip_atomic_store(rdy_my, 0x3F800000u, __ATOMIC_RELEASE, __HIP_MEMORY_SCOPE_AGENT);
        while (__hip_atomic_load(rdy_pt, __ATOMIC_ACQUIRE, __HIP_MEMORY_SCOPE_AGENT)
               != 0x3F800000u) {}
    }
    __syncthreads();

    for (int s = 0; s < SS; ++s) {
        const int par = s & 1;
        // ---- publish step s: h row s-1 (already drained by barrier) + fc partials
        if (t == 0 && s > 0) {
            fcp_my[((s - 1) & 1) * 2 + 0] = outp[0][0] + outp[0][1];
            fcp_my[((s - 1) & 1) * 2 + 1] = outp[1][0] + outp[1][1];
            __threadfence();
            __hip_atomic_store(flag_my, (u32)s, __ATOMIC_RELEASE, __HIP_MEMORY_SCOPE_AGENT);
        }
        // ---- x prefetch for s+1 (wave 4 lanes)
        float xpre = 0.f; const int xi = t - 256;
        if (xi >= 0 && xi < 64) {
            const int xe = xi >> 5, xl = xi & 31;
            const int sn = (s + 1 < SS) ? s + 1 : SS - 1;
            xpre = x_d[(size_t)(xe ? e1 : e0) * SS * FD + (size_t)sn * FD + xl];
        }
        // ---- x-projection share (rows 8kq..8kq+7)
        float acc00 = 0, acc01 = 0, acc02 = 0, acc10 = 0, acc11 = 0, acc12 = 0;
        {
            const int x0 = 8 * kq;
#pragma unroll
            for (int jj = 0; jj < 8; ++jj) {
                const float xv0 = xbuf[par][0][x0 + jj], xv1 = xbuf[par][1][x0 + jj];
                const float w0 = sm_wih[x0 + jj][0][a];
                const float w1 = sm_wih[x0 + jj][1][a];
                const float w2 = sm_wih[x0 + jj][2][a];
                acc00 = fmaf(xv0, w0, acc00); acc01 = fmaf(xv0, w1, acc01); acc02 = fmaf(xv0, w2, acc02);
                acc10 = fmaf(xv1, w0, acc10); acc11 = fmaf(xv1, w1, acc11); acc12 = fmaf(xv1, w2, acc12);
            }
        }
        // ---- h @ W_hh quarter (skip at s=0: h=0)
        if (s > 0) {
            if (own_half) {
                const float4* h0 = reinterpret_cast<const float4*>(&hbuf[0][64 * (kq & 1)]);
                const float4* h1 = reinterpret_cast<const float4*>(&hbuf[1][64 * (kq & 1)]);
#pragma unroll
                for (int j4 = 0; j4 < 16; ++j4) {
                    const float4 A = h0[j4], B = h1[j4];
                    MAC16(A, B, j4)
                }
            } else {
                while ((int)__hip_atomic_load(flag_pt, __ATOMIC_ACQUIRE,
                                              __HIP_MEMORY_SCOPE_AGENT) < s) {}
                const float4* h0 = reinterpret_cast<const float4*>(
                    hn_out + ((size_t)e0 * SS + (s - 1)) * HH + 128 * (1 ^ role) + 64 * (kq & 1));
                const float4* h1 = reinterpret_cast<const float4*>(
                    hn_out + ((size_t)e1 * SS + (s - 1)) * HH + 128 * (1 ^ role) + 64 * (kq & 1));
#pragma unroll
                for (int j4 = 0; j4 < 16; ++j4) {
                    const float4 A = h0[j4], B = h1[j4];
                    MAC16(A, B, j4)
                }
            }
        }
        // ---- deferred fc head write for s-1 (role 0; wave-4 lane already acquired)
        if (role == 0 && t == 256 && s > 0) {
            const int pp = (s - 1) & 1;
            out_fc[(size_t)e0 * SS + (s - 1)] = outp[0][0] + outp[0][1] + fcp_pt[pp * 2 + 0] + bfc;
            out_fc[(size_t)e1 * SS + (s - 1)] = outp[1][0] + outp[1][1] + fcp_pt[pp * 2 + 1] + bfc;
        }
        // ---- partials + land prefetched x
        sm_part[0][0][kq][a] = acc00; sm_part[0][1][kq][a] = acc01; sm_part[0][2][kq][a] = acc02;
        sm_part[1][0][kq][a] = acc10; sm_part[1][1][kq][a] = acc11; sm_part[1][2][kq][a] = acc12;
        if (xi >= 0 && xi < 64) xbuf[par ^ 1][xi >> 5][xi & 31] = xpre;
        __syncthreads();

        // ---- gate phase (threads 0..255)
        if (t < 256) {
            const int e = t >> 7, i = t & 127;
            float f = sm_part[e][0][0][i] + sm_part[e][0][1][i] + sm_part[e][0][2][i] + sm_part[e][0][3][i] + bfv;
            float o = sm_part[e][1][0][i] + sm_part[e][1][1][i] + sm_part[e][1][2][i] + sm_part[e][1][3][i] + bov;
            float g = sm_part[e][2][0][i] + sm_part[e][2][1][i] + sm_part[e][2][2][i] + sm_part[e][2][3][i] + bgv;
            const float sf = 1.f / (1.f + __expf(-f));
            const float so = 1.f / (1.f + __expf(-o));
            const float tg = 1.f - 2.f / (1.f + __expf(2.f * g));   // safe tanh
            c_state = sf * c_state + igv * tg;
            const float tc = 1.f - 2.f / (1.f + __expf(2.f * c_state));
            const float h1 = so * tc;
            hbuf[e][i] = h1;
            const size_t oidx = ((size_t)(e ? e1 : e0) * SS + s) * HH + 128 * role + i;
            hn_out[oidx] = h1;
            cn_out[oidx] = c_state;
            float psum = h1 * wfcv;
#pragma unroll
            for (int d = 32; d > 0; d >>= 1) psum += __shfl_down(psum, d);
            if ((t & 63) == 0) outp[t >> 7][(t >> 6) & 1] = psum;
        }
        __syncthreads();   // implicit vmcnt(0): hn/cn stores drained before next publish
    }

    // ---- epilogue: final publish + fc row 364
    if (t == 0) {
        fcp_my[0] = outp[0][0] + outp[0][1];
        fcp_my[1] = outp[1][0] + outp[1][1];
        __threadfence();
        __hip_atomic_store(flag_my, (u32)SS, __ATOMIC_RELEASE, __HIP_MEMORY_SCOPE_AGENT);
        if (role == 0) {
            while ((int)__hip_atomic_load(flag_pt, __ATOMIC_ACQUIRE,
                                          __HIP_MEMORY_SCOPE_AGENT) < SS) {}
            out_fc[(size_t)e0 * SS + (SS - 1)] = outp[0][0] + outp[0][1] + fcp_pt[0] + bfc;
            out_fc[(size_t)e1 * SS + (SS - 1)] = outp[1][0] + outp[1][1] + fcp_pt[1] + bfc;
        }
    }
}

extern "C" void kernel_launch(void* const* d_in, const int* in_sizes, int n_in,
                              void* d_out, int out_size, void* d_ws, size_t ws_size,
                              hipStream_t stream) {
    const float* x_d    = (const float*)d_in[0];
    const float* x_s    = (const float*)d_in[1];
    const float* W_ih   = (const float*)d_in[2];
    const float* W_hh   = (const float*)d_in[3];
    const float* W_sh   = (const float*)d_in[4];
    const float* bias   = (const float*)d_in[5];
    const float* bias_s = (const float*)d_in[6];
    const float* W_fc   = (const float*)d_in[7];
    const float* b_fc   = (const float*)d_in[8];

    ealstm_kernel<<<dim3(BB), dim3(NT), 0, stream>>>(
        x_d, x_s, W_ih, W_hh, W_sh, bias, bias_s, W_fc, b_fc,
        (float*)d_out, (u32*)d_ws);
}